// Round 9
// baseline (256.185 us; speedup 1.0000x reference)
//
#include <hip/hip_runtime.h>
#include <hip/hip_bf16.h>

// B=2, S=2048, H=16, D=128, fp32 in/out, causal, interleaved RoPE.
// pass1 (pack_all): rope(Q)*scale*log2e, rope(K), V^T as bf16 in lane-linear
// fragment-ordered 64x128 tiles (group*1024B + lane*16B) in d_ws.
// pass2 (fattn4): flash attention, BQ=128 (4 waves x 32 q-rows), in-register
// P (swapped QK + key-permuted V^T pack), max-free exp2 softmax, K staged in
// LDS (dbuf DMA), V direct-from-L2 into registers.
// XCD-pinned grid (bh fastest -> linear%8 = bh%8). NT Q-loads + NT O-stores.
// Heavy-first qt (best measured; all pairing remaps regressed -- abandoned).
// THIS ROUND: counted-vmcnt software pipeline (T3/T4). __syncthreads (which
// drains vmcnt(0) and re-serializes every iter at 1-2 waves/SIMD) replaced
// by s_waitcnt vmcnt(16) + raw s_barrier: drains only the 4 K-DMAs, leaves
// the 16 V loads in flight across the barrier. V register-double-buffered
// (bvvA/bvvB, 2-body unroll; nkt always even -> static indexing). Both K and
// V now prefetch a FULL iteration ahead (~2000cyc) covering L3 latency
// (K+V 8MB/XCD > 4MB L2 -> ~half the staging is L3-served at ~700-900cyc,
// fully exposed before this change).
#define B_  2
#define S_  2048
#define H_  16
#define D_  128
#define BQ  128
#define SH  (H_ * D_)        // 2048
#define NT  (S_ / 64)        // 32 pack tiles (64 rows each) per (b,h)
#define NTQ (S_ / BQ)        // 16 q-blocks per (b,h)
#define TILE_US 8192         // ushorts per 64x128 bf16 tile (16KB)

typedef __attribute__((ext_vector_type(8))) short bf16x8;
typedef __attribute__((ext_vector_type(4))) float f32x4;
typedef __attribute__((ext_vector_type(4))) unsigned int u32x4;

__device__ __forceinline__ ushort f2bf(float x) {
  union { float f; unsigned u; } c; c.f = x;
  unsigned u = c.u;
  return (ushort)((u + 0x7FFFu + ((u >> 16) & 1u)) >> 16);
}

// async global->LDS, 16B per lane; LDS dst = wave-uniform base + lane*16.
__device__ __forceinline__ void gload_lds16(const ushort* g, ushort* l) {
  __builtin_amdgcn_global_load_lds((const __attribute__((address_space(1))) void*)g,
                                   (__attribute__((address_space(3))) void*)l,
                                   16, 0, 0);
}

// non-temporal 16B load (streaming: don't let Q evict K/V from L2)
__device__ __forceinline__ bf16x8 ntload8(const ushort* p) {
  union { u32x4 u; bf16x8 v; } c;
  c.u = __builtin_nontemporal_load((const u32x4*)p);
  return c.v;
}

// pack two f32 -> one dword of 2 bf16 (RNE), single instruction
__device__ __forceinline__ unsigned cvt_pk_bf16(float lo, float hi) {
  unsigned d;
  asm("v_cvt_pk_bf16_f32 %0, %1, %2" : "=v"(d) : "v"(lo), "v"(hi));
  return d;
}

// ---------------------------------------------------------------------------
// Pass 1: packs rope(Q)*QS, rope(K), V^T into lane-linear fragment tiles.
// Grid (bh, t): XCD = bh%8 == consuming XCD of fattn4.
// K/Q tile: pos = ((col>>5)*4 + (row>>4))*64 + ((row&15) | (((col>>3)&3)<<4))
// V^T tile: group (ks2*8+db), lane (dim&15)|(quad<<4); element j holds
//           key = ks2*32 + (j>>2)*16 + quad*4 + (j&3)  [matches in-reg P]
// ---------------------------------------------------------------------------
__global__ __launch_bounds__(256)
void pack_all(const float* __restrict__ qg, const float* __restrict__ kg,
              const float* __restrict__ vg, const float* __restrict__ fg,
              ushort* __restrict__ qr, ushort* __restrict__ kr,
              ushort* __restrict__ vt) {
  __shared__ float sv[64][133];
  const int bhp = blockIdx.x;          // 0..31, %8 selects XCD
  const int t   = blockIdx.y;
  const int b   = bhp >> 4;
  const int h   = bhp & 15;
  const int tid = threadIdx.x;
  const float QS = 0.08838834764831845f * 1.4426950408889634f; // 1/sqrt(128)*log2(e)
  const size_t tbase = ((size_t)(b * H_ + h) * NT + t) * TILE_US;

  #pragma unroll
  for (int c = 0; c < 4; c++) {
    const int idx = tid + 256 * c;   // 0..1023
    const int row = idx >> 4;
    const int cu  = idx & 15;
    const int col = cu * 8;
    const int s   = t * 64 + row;
    const size_t goff = ((size_t)(b * S_ + s)) * SH + (size_t)h * D_ + col;

    const float4 f0 = *(const float4*)(fg + (size_t)s * D_ + col);
    const float4 f1 = *(const float4*)(fg + (size_t)s * D_ + col + 4);
    const float4 qx0 = *(const float4*)(qg + goff);
    const float4 qx1 = *(const float4*)(qg + goff + 4);
    const float4 kx0 = *(const float4*)(kg + goff);
    const float4 kx1 = *(const float4*)(kg + goff + 4);
    const float4 vx0 = *(const float4*)(vg + goff);
    const float4 vx1 = *(const float4*)(vg + goff + 4);

    *(float4*)&sv[row][col]     = vx0;
    *(float4*)&sv[row][col + 4] = vx1;

    union { ushort s[8]; uint4 v; } pq, pk;
    pq.s[0] = f2bf((f0.x*qx0.x - f0.y*qx0.y) * QS);
    pq.s[1] = f2bf((f0.y*qx0.x + f0.x*qx0.y) * QS);
    pq.s[2] = f2bf((f0.z*qx0.z - f0.w*qx0.w) * QS);
    pq.s[3] = f2bf((f0.w*qx0.z + f0.z*qx0.w) * QS);
    pq.s[4] = f2bf((f1.x*qx1.x - f1.y*qx1.y) * QS);
    pq.s[5] = f2bf((f1.y*qx1.x + f1.x*qx1.y) * QS);
    pq.s[6] = f2bf((f1.z*qx1.z - f1.w*qx1.w) * QS);
    pq.s[7] = f2bf((f1.w*qx1.z + f1.z*qx1.w) * QS);
    pk.s[0] = f2bf(f0.x*kx0.x - f0.y*kx0.y);
    pk.s[1] = f2bf(f0.y*kx0.x + f0.x*kx0.y);
    pk.s[2] = f2bf(f0.z*kx0.z - f0.w*kx0.w);
    pk.s[3] = f2bf(f0.w*kx0.z + f0.z*kx0.w);
    pk.s[4] = f2bf(f1.x*kx1.x - f1.y*kx1.y);
    pk.s[5] = f2bf(f1.y*kx1.x + f1.x*kx1.y);
    pk.s[6] = f2bf(f1.z*kx1.z - f1.w*kx1.w);
    pk.s[7] = f2bf(f1.w*kx1.z + f1.z*kx1.w);

    const int pos = ((cu >> 2) * 4 + (row >> 4)) * 64 + ((row & 15) | ((cu & 3) << 4));
    *(uint4*)(qr + tbase + (size_t)pos * 8) = pq.v;
    *(uint4*)(kr + tbase + (size_t)pos * 8) = pk.v;
  }
  __syncthreads();

  #pragma unroll
  for (int c = 0; c < 4; c++) {
    const int u2  = tid + 256 * c;     // = group*64 + lane
    const int g2  = u2 >> 6;
    const int ln  = u2 & 63;
    const int dim = (g2 & 7) * 16 + (ln & 15);
    const int ks2 = g2 >> 3;
    const int qd  = ln >> 4;
    union { ushort s[8]; uint4 v; } p;
    #pragma unroll
    for (int j = 0; j < 8; j++) {
      const int key = ks2 * 32 + (j >> 2) * 16 + qd * 4 + (j & 3);
      p.s[j] = f2bf(sv[key][dim]);
    }
    *(uint4*)(vt + tbase + (size_t)u2 * 8) = p.v;
  }
}

// ---------------------------------------------------------------------------
// Pass 2 pipeline body. Static cur/nxt register buffers (rule #20).
// Steady-state vmcnt FIFO per wave at body top: [KDMA(kt) x4, V(kt) x16]
// (iter 0: [Q x16, KDMA(0) x4, V(0) x16] -> vmcnt(16) drains Q+KDMA too).
// ---------------------------------------------------------------------------
__device__ __forceinline__ void fa_body(
    int kt, int nkt, int qt, int wv, int lane, int l15, int quad, int rowmax,
    const ushort* __restrict__ ktb, const ushort* __restrict__ vtb,
    ushort (*sK)[TILE_US],
    bf16x8 (&cur)[2][8], bf16x8 (&nxt)[2][8], bf16x8 (&afq)[2][4],
    float (&rs)[2], f32x4 (&o_acc)[2][8]) {
  // drain only the K-DMAs (4 oldest); V loads stay in flight across barrier
  asm volatile("s_waitcnt vmcnt(16)" ::: "memory");
  __builtin_amdgcn_s_barrier();
  __builtin_amdgcn_sched_barrier(0);

  // issue next tile: K-DMA first (so next top's vmcnt(16) drains exactly it),
  // then V register loads into nxt. Both get a full iteration to land.
  if (kt + 1 < nkt) {
    const ushort* ksrc = ktb + (size_t)(kt + 1) * TILE_US;
    #pragma unroll
    for (int c = 0; c < 4; c++) {
      const int g = wv * 4 + c;
      gload_lds16(ksrc + g * 512 + lane * 8, &sK[(kt + 1) & 1][g * 512 + lane * 8]);
    }
    const ushort* vsrc = vtb + (size_t)(kt + 1) * TILE_US;
    #pragma unroll
    for (int ks = 0; ks < 2; ks++)
      #pragma unroll
      for (int dt = 0; dt < 8; dt++)
        nxt[ks][dt] = *(const bf16x8*)(vsrc + (size_t)((ks * 8 + dt) * 64 + lane) * 8);
  }
  __builtin_amdgcn_sched_barrier(0);   // pin issue cluster above compute

  // wave-uniform: skip tiles entirely above the diagonal for this wave's rows
  if (kt * 64 <= rowmax) {
    // ---- S^T = K·Qs : swapped operands; K frag read once, used 2x ----
    f32x4 sc[2][4];
    #pragma unroll
    for (int rh = 0; rh < 2; rh++)
      #pragma unroll
      for (int nt = 0; nt < 4; nt++) sc[rh][nt] = (f32x4)0.0f;
    #pragma unroll
    for (int nt = 0; nt < 4; nt++) {
      #pragma unroll
      for (int ks = 0; ks < 4; ks++) {
        const bf16x8 bk_ = *(const bf16x8*)&sK[kt & 1][(size_t)((ks * 4 + nt) * 64 + lane) * 8];
        sc[0][nt] = __builtin_amdgcn_mfma_f32_16x16x32_bf16(bk_, afq[0][ks], sc[0][nt], 0, 0, 0);
        sc[1][nt] = __builtin_amdgcn_mfma_f32_16x16x32_bf16(bk_, afq[1][ks], sc[1][nt], 0, 0, 0);
      }
    }

    // ---- causal mask: q = l15, k = quad*4+r (only last 2 tiles cross) ----
    if (kt >= 2 * qt) {
      #pragma unroll
      for (int rh = 0; rh < 2; rh++) {
        const int qg = qt * 128 + wv * 32 + rh * 16 + l15;
        #pragma unroll
        for (int nt = 0; nt < 4; nt++) {
          const int kg = kt * 64 + nt * 16 + quad * 4;
          #pragma unroll
          for (int r = 0; r < 4; r++)
            if (kg + r > qg) sc[rh][nt][r] = -1e30f;
        }
      }
    }

    // ---- max-free softmax, P packed fully in-register ----
    bf16x8 ap[2][2];
    #pragma unroll
    for (int rh = 0; rh < 2; rh++) {
      float p[4][4];
      #pragma unroll
      for (int nt = 0; nt < 4; nt++)
        #pragma unroll
        for (int r = 0; r < 4; r++) {
          p[nt][r] = __builtin_amdgcn_exp2f(sc[rh][nt][r]);
          rs[rh] += p[nt][r];
        }
      #pragma unroll
      for (int ks = 0; ks < 2; ks++) {
        union { unsigned u[4]; bf16x8 v; } pk_;
        #pragma unroll
        for (int m = 0; m < 4; m++) {
          const int nt = ks * 2 + (m >> 1);
          pk_.u[m] = cvt_pk_bf16(p[nt][2 * (m & 1)], p[nt][2 * (m & 1) + 1]);
        }
        ap[rh][ks] = pk_.v;
      }
    }

    // ---- O += P·V : pure register MFMA; compiler waits cur's loads ----
    #pragma unroll
    for (int dt = 0; dt < 8; dt++) {
      #pragma unroll
      for (int ks = 0; ks < 2; ks++) {
        o_acc[0][dt] = __builtin_amdgcn_mfma_f32_16x16x32_bf16(ap[0][ks], cur[ks][dt], o_acc[0][dt], 0, 0, 0);
        o_acc[1][dt] = __builtin_amdgcn_mfma_f32_16x16x32_bf16(ap[1][ks], cur[ks][dt], o_acc[1][dt], 0, 0, 0);
      }
    }
  }
}

__global__ __launch_bounds__(256, 2)
void fattn4(const ushort* __restrict__ qr, const ushort* __restrict__ kr,
            const ushort* __restrict__ vt, float* __restrict__ og) {
  __shared__ __align__(16) ushort sK[2][TILE_US];

  const int bh_  = blockIdx.x;                   // 0..31; bh_%8 selects XCD
  const int qt   = NTQ - 1 - (int)blockIdx.y;    // heavy blocks first
  const int tid  = threadIdx.x;
  const int wv   = tid >> 6;
  const int lane = tid & 63;
  const int l15  = lane & 15;
  const int quad = lane >> 4;

  const size_t bh = (size_t)bh_;
  const ushort* ktb = kr + bh * NT * TILE_US;
  const ushort* vtb = vt + bh * NT * TILE_US;

  // Q fragments (non-temporal, issued FIRST -> oldest in vmcnt FIFO).
  bf16x8 afq[2][4];
  {
    const ushort* qtb64 = qr + (bh * NT + 2 * qt + (wv >> 1)) * TILE_US;
    const int rbb = (wv & 1) * 2;
    #pragma unroll
    for (int rh = 0; rh < 2; rh++)
      #pragma unroll
      for (int ks = 0; ks < 4; ks++)
        afq[rh][ks] = ntload8(qtb64 + (size_t)((ks * 4 + rbb + rh) * 64 + lane) * 8);
  }

  float rs[2] = {0.0f, 0.0f};
  f32x4 o_acc[2][8];
  #pragma unroll
  for (int rh = 0; rh < 2; rh++)
    #pragma unroll
    for (int dt = 0; dt < 8; dt++) o_acc[rh][dt] = (f32x4)0.0f;

  // prologue: K-DMA(0), then V(0) into bvvA (matches steady-state FIFO)
  #pragma unroll
  for (int c = 0; c < 4; c++) {
    const int g = wv * 4 + c;
    gload_lds16(ktb + g * 512 + lane * 8, &sK[0][g * 512 + lane * 8]);
  }
  bf16x8 bvvA[2][8], bvvB[2][8];
  #pragma unroll
  for (int ks = 0; ks < 2; ks++)
    #pragma unroll
    for (int dt = 0; dt < 8; dt++)
      bvvA[ks][dt] = *(const bf16x8*)(vtb + (size_t)((ks * 8 + dt) * 64 + lane) * 8);

  const int rowmax = qt * BQ + wv * 32 + 31;     // last q-row owned by this wave
  const int nkt = 2 * qt + 2;                    // always even
  for (int kt = 0; kt < nkt; kt += 2) {
    fa_body(kt,     nkt, qt, wv, lane, l15, quad, rowmax, ktb, vtb, sK, bvvA, bvvB, afq, rs, o_acc);
    fa_body(kt + 1, nkt, qt, wv, lane, l15, quad, rowmax, ktb, vtb, sK, bvvB, bvvA, afq, rs, o_acc);
  }

  // ---- epilogue: cross-quad row-sum reduce (rows live at q=l15), then
  // redistribute to O rows (q = quad*4+r), normalize, NT store ----
  float* ob = og + (bh * S_ + (size_t)qt * BQ) * D_;
  #pragma unroll
  for (int rh = 0; rh < 2; rh++) {
    float t = rs[rh];
    t += __shfl_xor(t, 16);
    t += __shfl_xor(t, 32);          // every lane: sum for its q = l15
    #pragma unroll
    for (int r = 0; r < 4; r++) {
      const float inv = 1.0f / __shfl(t, quad * 4 + r);  // sum for q=quad*4+r
      const int row = wv * 32 + rh * 16 + quad * 4 + r;
      #pragma unroll
      for (int dt = 0; dt < 8; dt++)
        __builtin_nontemporal_store(o_acc[rh][dt][r] * inv,
                                    &ob[(size_t)row * D_ + dt * 16 + l15]);
    }
  }
}

extern "C" void kernel_launch(void* const* d_in, const int* in_sizes, int n_in,
                              void* d_out, int out_size, void* d_ws, size_t ws_size,
                              hipStream_t stream) {
  const float* q = (const float*)d_in[0];
  const float* k = (const float*)d_in[1];
  const float* v = (const float*)d_in[2];
  const float* f = (const float*)d_in[3];
  float* o = (float*)d_out;

  const size_t NELT = (size_t)B_ * S_ * H_ * D_;   // 8388608
  ushort* qr = (ushort*)d_ws;
  ushort* kr = qr + NELT;
  ushort* vt = kr + NELT;

  pack_all<<<dim3(B_ * H_, NT), dim3(256), 0, stream>>>(q, k, v, f, qr, kr, vt);
  fattn4<<<dim3(B_ * H_, NTQ), dim3(256), 0, stream>>>(qr, kr, vt, o);
}

// Round 10
// 191.165 us; speedup vs baseline: 1.3401x; 1.3401x over previous
//
#include <hip/hip_runtime.h>
#include <hip/hip_bf16.h>

// B=2, S=2048, H=16, D=128, fp32 in/out, causal, interleaved RoPE.
// pass1 (pack_all): rope(Q)*scale*log2e, rope(K), V^T as bf16 in lane-linear
// fragment-ordered 64x128 tiles (group*1024B + lane*16B) in d_ws.
// pass2 (fattn2): flash attention, BQ=64 (2 waves x 32 q-rows), in-register
// P (swapped QK + key-permuted V^T pack), max-free exp2 softmax, K-only
// double-buffered global_load_lds staging (32KB), V direct-from-L2 into
// registers (single buffer -- R9's V double-buffer spilled: WRITE_SIZE 144MB).
// THIS ROUND: R7's 4-blocks/CU structure (1024 blocks x 128 thr,
// __launch_bounds__(128,2)) combined with R8's vmcnt-FIFO fix (V loads
// issued FIRST after the barrier, before the K-DMA prefetch, so PV's
// implicit vmcnt wait doesn't drain the in-flight K prefetch). R8 proved
// the ordering fix is worth ~17us on BQ=128; R7 never had it. 4 co-resident
// blocks/CU give 2-4x latency hiding vs R8's effective 1 block/CU.
// XCD-pinned grid (bh fastest -> linear%8 = bh%8). NT Q-loads + NT O-stores.
#define B_  2
#define S_  2048
#define H_  16
#define D_  128
#define SH  (H_ * D_)        // 2048
#define NT  (S_ / 64)        // 32 pack tiles (64 rows each) per (b,h)
#define NQ2 (S_ / 64)        // 32 q-blocks (64 rows) per (b,h)
#define TILE_US 8192         // ushorts per 64x128 bf16 tile (16KB)

typedef __attribute__((ext_vector_type(8))) short bf16x8;
typedef __attribute__((ext_vector_type(4))) float f32x4;
typedef __attribute__((ext_vector_type(4))) unsigned int u32x4;

__device__ __forceinline__ ushort f2bf(float x) {
  union { float f; unsigned u; } c; c.f = x;
  unsigned u = c.u;
  return (ushort)((u + 0x7FFFu + ((u >> 16) & 1u)) >> 16);
}

// async global->LDS, 16B per lane; LDS dst = wave-uniform base + lane*16.
__device__ __forceinline__ void gload_lds16(const ushort* g, ushort* l) {
  __builtin_amdgcn_global_load_lds((const __attribute__((address_space(1))) void*)g,
                                   (__attribute__((address_space(3))) void*)l,
                                   16, 0, 0);
}

// non-temporal 16B load (streaming: don't let Q evict K/V from L2)
__device__ __forceinline__ bf16x8 ntload8(const ushort* p) {
  union { u32x4 u; bf16x8 v; } c;
  c.u = __builtin_nontemporal_load((const u32x4*)p);
  return c.v;
}

// pack two f32 -> one dword of 2 bf16 (RNE), single instruction
__device__ __forceinline__ unsigned cvt_pk_bf16(float lo, float hi) {
  unsigned d;
  asm("v_cvt_pk_bf16_f32 %0, %1, %2" : "=v"(d) : "v"(lo), "v"(hi));
  return d;
}

// ---------------------------------------------------------------------------
// Pass 1: packs rope(Q)*QS, rope(K), V^T into lane-linear fragment tiles.
// Grid (bh, t): XCD = bh%8 == consuming XCD of fattn2.
// K/Q tile: pos = ((col>>5)*4 + (row>>4))*64 + ((row&15) | (((col>>3)&3)<<4))
// V^T tile: group (ks2*8+db), lane (dim&15)|(quad<<4); element j holds
//           key = ks2*32 + (j>>2)*16 + quad*4 + (j&3)  [matches in-reg P]
// ---------------------------------------------------------------------------
__global__ __launch_bounds__(256)
void pack_all(const float* __restrict__ qg, const float* __restrict__ kg,
              const float* __restrict__ vg, const float* __restrict__ fg,
              ushort* __restrict__ qr, ushort* __restrict__ kr,
              ushort* __restrict__ vt) {
  __shared__ float sv[64][133];
  const int bhp = blockIdx.x;          // 0..31, %8 selects XCD
  const int t   = blockIdx.y;
  const int b   = bhp >> 4;
  const int h   = bhp & 15;
  const int tid = threadIdx.x;
  const float QS = 0.08838834764831845f * 1.4426950408889634f; // 1/sqrt(128)*log2(e)
  const size_t tbase = ((size_t)(b * H_ + h) * NT + t) * TILE_US;

  #pragma unroll
  for (int c = 0; c < 4; c++) {
    const int idx = tid + 256 * c;   // 0..1023
    const int row = idx >> 4;
    const int cu  = idx & 15;
    const int col = cu * 8;
    const int s   = t * 64 + row;
    const size_t goff = ((size_t)(b * S_ + s)) * SH + (size_t)h * D_ + col;

    const float4 f0 = *(const float4*)(fg + (size_t)s * D_ + col);
    const float4 f1 = *(const float4*)(fg + (size_t)s * D_ + col + 4);
    const float4 qx0 = *(const float4*)(qg + goff);
    const float4 qx1 = *(const float4*)(qg + goff + 4);
    const float4 kx0 = *(const float4*)(kg + goff);
    const float4 kx1 = *(const float4*)(kg + goff + 4);
    const float4 vx0 = *(const float4*)(vg + goff);
    const float4 vx1 = *(const float4*)(vg + goff + 4);

    *(float4*)&sv[row][col]     = vx0;
    *(float4*)&sv[row][col + 4] = vx1;

    union { ushort s[8]; uint4 v; } pq, pk;
    pq.s[0] = f2bf((f0.x*qx0.x - f0.y*qx0.y) * QS);
    pq.s[1] = f2bf((f0.y*qx0.x + f0.x*qx0.y) * QS);
    pq.s[2] = f2bf((f0.z*qx0.z - f0.w*qx0.w) * QS);
    pq.s[3] = f2bf((f0.w*qx0.z + f0.z*qx0.w) * QS);
    pq.s[4] = f2bf((f1.x*qx1.x - f1.y*qx1.y) * QS);
    pq.s[5] = f2bf((f1.y*qx1.x + f1.x*qx1.y) * QS);
    pq.s[6] = f2bf((f1.z*qx1.z - f1.w*qx1.w) * QS);
    pq.s[7] = f2bf((f1.w*qx1.z + f1.z*qx1.w) * QS);
    pk.s[0] = f2bf(f0.x*kx0.x - f0.y*kx0.y);
    pk.s[1] = f2bf(f0.y*kx0.x + f0.x*kx0.y);
    pk.s[2] = f2bf(f0.z*kx0.z - f0.w*kx0.w);
    pk.s[3] = f2bf(f0.w*kx0.z + f0.z*kx0.w);
    pk.s[4] = f2bf(f1.x*kx1.x - f1.y*kx1.y);
    pk.s[5] = f2bf(f1.y*kx1.x + f1.x*kx1.y);
    pk.s[6] = f2bf(f1.z*kx1.z - f1.w*kx1.w);
    pk.s[7] = f2bf(f1.w*kx1.z + f1.z*kx1.w);

    const int pos = ((cu >> 2) * 4 + (row >> 4)) * 64 + ((row & 15) | ((cu & 3) << 4));
    *(uint4*)(qr + tbase + (size_t)pos * 8) = pq.v;
    *(uint4*)(kr + tbase + (size_t)pos * 8) = pk.v;
  }
  __syncthreads();

  #pragma unroll
  for (int c = 0; c < 4; c++) {
    const int u2  = tid + 256 * c;     // = group*64 + lane
    const int g2  = u2 >> 6;
    const int ln  = u2 & 63;
    const int dim = (g2 & 7) * 16 + (ln & 15);
    const int ks2 = g2 >> 3;
    const int qd  = ln >> 4;
    union { ushort s[8]; uint4 v; } p;
    #pragma unroll
    for (int j = 0; j < 8; j++) {
      const int key = ks2 * 32 + (j >> 2) * 16 + qd * 4 + (j & 3);
      p.s[j] = f2bf(sv[key][dim]);
    }
    *(uint4*)(vt + tbase + (size_t)u2 * 8) = p.v;
  }
}

// ---------------------------------------------------------------------------
// Pass 2: flash attention, 2 waves x 32 q-rows (BQ=64), in-register P,
// max-free softmax. Swapped QK: sc = mfma(K_frag, Q_frag) -> S^T with
// q = lane&15, k = kt*64 + nt*16 + quad*4 + r. K staged in LDS (dbuf DMA);
// V fragments loaded directly from L2-resident global, issued BEFORE the
// K prefetch (vmcnt FIFO: PV's wait must not drain the K-DMA).
// __launch_bounds__(128,2): 2 waves/EU -> 4 blocks/CU co-resident.
// ---------------------------------------------------------------------------
__global__ __launch_bounds__(128, 2)
void fattn2(const ushort* __restrict__ qr, const ushort* __restrict__ kr,
            const ushort* __restrict__ vt, float* __restrict__ og) {
  __shared__ __align__(16) ushort sK[2][TILE_US];

  const int bh_  = blockIdx.x;                   // 0..31; bh_%8 selects XCD
  const int qt   = NQ2 - 1 - (int)blockIdx.y;    // heavy blocks first, 0..31
  const int tid  = threadIdx.x;
  const int wv   = tid >> 6;                     // 0..1
  const int lane = tid & 63;
  const int l15  = lane & 15;
  const int quad = lane >> 4;

  const size_t bh = (size_t)bh_;
  const ushort* ktb = kr + bh * NT * TILE_US;
  const ushort* vtb = vt + bh * NT * TILE_US;

  // Q fragments (non-temporal: read-once stream, keep L2 for K/V).
  // Wave wv covers q-rows [wv*32, wv*32+32); pack-tile row-block = wv*2+rh.
  bf16x8 afq[2][4];
  {
    const ushort* qtb64 = qr + (bh * NT + qt) * TILE_US;
    #pragma unroll
    for (int rh = 0; rh < 2; rh++)
      #pragma unroll
      for (int ks = 0; ks < 4; ks++)
        afq[rh][ks] = ntload8(qtb64 + (size_t)((ks * 4 + wv * 2 + rh) * 64 + lane) * 8);
  }

  float rs[2] = {0.0f, 0.0f};
  f32x4 o_acc[2][8];
  #pragma unroll
  for (int rh = 0; rh < 2; rh++)
    #pragma unroll
    for (int dt = 0; dt < 8; dt++) o_acc[rh][dt] = (f32x4)0.0f;

  // prologue: stage K tile 0 into buffer 0 (8 x 1KB chunks per wave)
  #pragma unroll
  for (int c = 0; c < 8; c++) {
    const int g = wv * 8 + c;
    gload_lds16(ktb + g * 512 + lane * 8, &sK[0][g * 512 + lane * 8]);
  }

  const int nkt = qt + 1;
  int buf = 0;
  for (int kt = 0; kt < nkt; kt++) {
    __syncthreads();   // drains K prefetch issued one full iteration ago

    // ---- V fragment loads for THIS tile, issued FIRST (vmcnt is FIFO:
    // PV's wait for these must not force the K-DMA below to drain) ----
    const ushort* vsrc = vtb + (size_t)kt * TILE_US;
    bf16x8 bvv[2][8];
    #pragma unroll
    for (int ks = 0; ks < 2; ks++)
      #pragma unroll
      for (int dt = 0; dt < 8; dt++)
        bvv[ks][dt] = *(const bf16x8*)(vsrc + (size_t)((ks * 8 + dt) * 64 + lane) * 8);
    __builtin_amdgcn_sched_barrier(0);   // pin: V issued before K-DMA + QK

    if (kt + 1 < nkt) {
      const ushort* ksrc = ktb + (size_t)(kt + 1) * TILE_US;
      #pragma unroll
      for (int c = 0; c < 8; c++) {
        const int g = wv * 8 + c;
        gload_lds16(ksrc + g * 512 + lane * 8, &sK[buf ^ 1][g * 512 + lane * 8]);
      }
    }

    // ---- S^T = K·Qs : swapped operands; K frag read once, used 2x ----
    f32x4 sc[2][4];
    #pragma unroll
    for (int rh = 0; rh < 2; rh++)
      #pragma unroll
      for (int nt = 0; nt < 4; nt++) sc[rh][nt] = (f32x4)0.0f;
    #pragma unroll
    for (int nt = 0; nt < 4; nt++) {
      #pragma unroll
      for (int ks = 0; ks < 4; ks++) {
        const bf16x8 bk_ = *(const bf16x8*)&sK[buf][(size_t)((ks * 4 + nt) * 64 + lane) * 8];
        sc[0][nt] = __builtin_amdgcn_mfma_f32_16x16x32_bf16(bk_, afq[0][ks], sc[0][nt], 0, 0, 0);
        sc[1][nt] = __builtin_amdgcn_mfma_f32_16x16x32_bf16(bk_, afq[1][ks], sc[1][nt], 0, 0, 0);
      }
    }

    // ---- causal mask: q = l15, k = quad*4+r (only diagonal tile) ----
    if (kt == qt) {
      #pragma unroll
      for (int rh = 0; rh < 2; rh++) {
        const int qg = qt * 64 + wv * 32 + rh * 16 + l15;
        #pragma unroll
        for (int nt = 0; nt < 4; nt++) {
          const int kg = kt * 64 + nt * 16 + quad * 4;
          #pragma unroll
          for (int r = 0; r < 4; r++)
            if (kg + r > qg) sc[rh][nt][r] = -1e30f;
        }
      }
    }

    // ---- max-free softmax, P packed fully in-register ----
    // A-frag element j of chunk ks holds k = ks*32+(j>>2)*16+quad*4+(j&3),
    // matching the V^T pack permutation.
    bf16x8 ap[2][2];
    #pragma unroll
    for (int rh = 0; rh < 2; rh++) {
      float p[4][4];
      #pragma unroll
      for (int nt = 0; nt < 4; nt++)
        #pragma unroll
        for (int r = 0; r < 4; r++) {
          p[nt][r] = __builtin_amdgcn_exp2f(sc[rh][nt][r]);
          rs[rh] += p[nt][r];
        }
      #pragma unroll
      for (int ks = 0; ks < 2; ks++) {
        union { unsigned u[4]; bf16x8 v; } pk_;
        #pragma unroll
        for (int m = 0; m < 4; m++) {
          const int nt = ks * 2 + (m >> 1);
          pk_.u[m] = cvt_pk_bf16(p[nt][2 * (m & 1)], p[nt][2 * (m & 1) + 1]);
        }
        ap[rh][ks] = pk_.v;
      }
    }

    // ---- O += P·V : pure register MFMA (V already in bvv) ----
    #pragma unroll
    for (int dt = 0; dt < 8; dt++) {
      #pragma unroll
      for (int ks = 0; ks < 2; ks++) {
        o_acc[0][dt] = __builtin_amdgcn_mfma_f32_16x16x32_bf16(ap[0][ks], bvv[ks][dt], o_acc[0][dt], 0, 0, 0);
        o_acc[1][dt] = __builtin_amdgcn_mfma_f32_16x16x32_bf16(ap[1][ks], bvv[ks][dt], o_acc[1][dt], 0, 0, 0);
      }
    }

    buf ^= 1;
  }

  // ---- epilogue: cross-quad row-sum reduce (rows live at q=l15), then
  // redistribute to O rows (q = quad*4+r), normalize, NT store ----
  float* ob = og + (bh * S_ + (size_t)qt * 64) * D_;
  #pragma unroll
  for (int rh = 0; rh < 2; rh++) {
    float t = rs[rh];
    t += __shfl_xor(t, 16);
    t += __shfl_xor(t, 32);          // every lane: sum for its q = l15
    #pragma unroll
    for (int r = 0; r < 4; r++) {
      const float inv = 1.0f / __shfl(t, quad * 4 + r);  // sum for q=quad*4+r
      const int row = wv * 32 + rh * 16 + quad * 4 + r;
      #pragma unroll
      for (int dt = 0; dt < 8; dt++)
        __builtin_nontemporal_store(o_acc[rh][dt][r] * inv,
                                    &ob[(size_t)row * D_ + dt * 16 + l15]);
    }
  }
}

extern "C" void kernel_launch(void* const* d_in, const int* in_sizes, int n_in,
                              void* d_out, int out_size, void* d_ws, size_t ws_size,
                              hipStream_t stream) {
  const float* q = (const float*)d_in[0];
  const float* k = (const float*)d_in[1];
  const float* v = (const float*)d_in[2];
  const float* f = (const float*)d_in[3];
  float* o = (float*)d_out;

  const size_t NELT = (size_t)B_ * S_ * H_ * D_;   // 8388608
  ushort* qr = (ushort*)d_ws;
  ushort* kr = qr + NELT;
  ushort* vt = kr + NELT;

  pack_all<<<dim3(B_ * H_, NT), dim3(256), 0, stream>>>(q, k, v, f, qr, kr, vt);
  fattn2<<<dim3(B_ * H_, NQ2), dim3(128), 0, stream>>>(qr, kr, vt, o);
}